// Round 8
// baseline (633.001 us; speedup 1.0000x reference)
//
#include <hip/hip_runtime.h>
#include <hip/hip_bf16.h>

// Problem constants
#define NT   1000
#define NS   2048
#define NH   16
#define NR   8
#define HS   256
#define TOUT 993   // NT - NR + 1

typedef __attribute__((ext_vector_type(8))) short short8;
typedef __attribute__((ext_vector_type(4))) float f32x4;

__device__ __forceinline__ ushort f2bf(float f) {
    union { float f; unsigned int u; } v; v.f = f;
    unsigned int u = v.u;
    return (ushort)((u + 0x7fffu + ((u >> 16) & 1u)) >> 16);
}
__device__ __forceinline__ float bf2f(ushort u) {
    union { unsigned int i; float f; } v; v.i = ((unsigned int)u) << 16; return v.f;
}
__device__ __forceinline__ unsigned int packbf2(float lo, float hi) {
    union { __hip_bfloat162 b; unsigned int u; } v;
    v.b = __float22bfloat162_rn(make_float2(lo, hi));
    return v.u;
}
__device__ __forceinline__ float sigf(float x) { return 1.f / (1.f + __expf(-x)); }
__device__ __forceinline__ float fast_tanh(float z) {
    float e = exp2f(z * 2.885390082f);
    return 1.f - 2.f * __builtin_amdgcn_rcpf(e + 1.f);
}
template<int CTRL>
__device__ __forceinline__ float dpp_add(float v) {
    int s = __builtin_amdgcn_update_dpp(0, __builtin_bit_cast(int, v), CTRL, 0xf, 0xf, true);
    return v + __builtin_bit_cast(float, s);
}
// async global->LDS DMA: zero result VGPRs, counted by vmcnt.
__device__ __forceinline__ void gll16(const void* g, void* l) {
    __builtin_amdgcn_global_load_lds((const __attribute__((address_space(1))) unsigned int*)g,
                                     (__attribute__((address_space(3))) unsigned int*)l, 16, 0, 0);
}
__device__ __forceinline__ void gll4(const void* g, void* l) {
    __builtin_amdgcn_global_load_lds((const __attribute__((address_space(1))) unsigned int*)g,
                                     (__attribute__((address_space(3))) unsigned int*)l, 4, 0, 0);
}

// params planes: 0 kp, 1 ks, 2 kd, 3 gd, 4 gl, 5 qb, 6 gi, 7 1-gi, 8 1-kd,
//                9 1-gd, 10 ge, 11..18 wrga
// ---------------- Kernel A: per-site setup ----------------
__global__ __launch_bounds__(256) void kA(
    const float* __restrict__ xc, const float* __restrict__ W_fc, const float* __restrict__ b_fc,
    const float* __restrict__ W_r, const float* __restrict__ b_r,
    const float* __restrict__ W_g, const float* __restrict__ b_g,
    const float* __restrict__ W_kin, const float* __restrict__ b_kin,
    const float* __restrict__ W_kout,
    float* __restrict__ stateK, float* __restrict__ params,
    ushort* __restrict__ Wt_g, ushort* __restrict__ whlo_g)
{
    __shared__ float xcs[32];
    __shared__ float hG[256];
    __shared__ float pGR[288];
    const int s = blockIdx.x, tid = threadIdx.x;

    if (tid < 32) xcs[tid] = xc[s * 32 + tid];
    __syncthreads();

    float acc = b_fc[tid];
#pragma unroll 8
    for (int k = 0; k < 32; ++k) acc = fmaf(xcs[k], W_fc[k * 256 + tid], acc);
    stateK[s * 256 + tid] = acc + b_kin[tid];
    hG[tid] = tanhf(acc);
    __syncthreads();

    for (int j = tid; j < 288; j += 256) {
        const float* W = (j < 144) ? W_g : W_r;
        const float* b = (j < 144) ? b_g : b_r;
        int col = (j < 144) ? j : (j - 144);
        float a = b[col];
#pragma unroll 4
        for (int k = 0; k < 256; ++k) a = fmaf(hG[k], W[k * 144 + col], a);
        pGR[j] = a;
    }
    __syncthreads();

    if (tid < 16) {
        const int h = tid;
        float g0 = pGR[h],       g1 = pGR[16 + h],  g2 = pGR[32 + h];
        float g3 = pGR[48 + h],  g4 = pGR[64 + h],  g5 = pGR[80 + h];
        float g6 = pGR[96 + h],  g7 = pGR[112 + h], g8 = pGR[128 + h];
        float kp = sigf(g0), ksg = sigf(g1), kd = sigf(g2), gd = sigf(g3);
        float t4 = sigf(g4) * 10.f; float gl = t4 * t4 * t4;
        float qb = fmaxf(g5, 0.f) * 0.1f;
        float gi = fminf(fmaxf(g7 * (1.f / 6.f) + 0.5f, 0.f), 1.f) * 0.5f;
        float ge = fmaxf(g8, 0.f);
        float m = g6;
        for (int o = 1; o < 16; o <<= 1) m = fmaxf(m, __shfl_xor(m, o));
        float e = __expf(g6 - m), esum = e;
        for (int o = 1; o < 16; o <<= 1) esum += __shfl_xor(esum, o);
        float ga = e / esum;
        float r[9], rm = -1e30f;
#pragma unroll
        for (int i = 0; i < 9; ++i) { r[i] = pGR[144 + h * 9 + i]; rm = fmaxf(rm, r[i]); }
        float er[9], es = 0.f;
#pragma unroll
        for (int i = 0; i < 9; ++i) { er[i] = __expf(r[i] - rm); es += er[i]; }
        float inv_es = 1.f / es, c = 0.f, wsum = 0.f, w[8];
#pragma unroll
        for (int i = 0; i < 8; ++i) {
            float si = er[i] * inv_es; c += si;
            float wi = fminf(c, 1.f - c + si);
            w[i] = wi; wsum += wi;
        }
        const int base = s * 16 + h;
        params[0 * 32768 + base] = kp;       params[1 * 32768 + base] = ksg;
        params[2 * 32768 + base] = kd;       params[3 * 32768 + base] = gd;
        params[4 * 32768 + base] = gl;       params[5 * 32768 + base] = qb;
        params[6 * 32768 + base] = gi;       params[7 * 32768 + base] = 1.f - gi;
        params[8 * 32768 + base] = 1.f - kd; params[9 * 32768 + base] = 1.f - gd;
        params[10 * 32768 + base] = ge;
        float sc = ga / wsum;
#pragma unroll
        for (int i = 0; i < 8; ++i) params[(11 + i) * 32768 + base] = w[i] * sc;
    }

    if (s == 0) {
        // Wt_g: W_kout^T in bf16, stride 264, rows permuted to match the
        // first-MFMA D layout (see kB).
        for (int i = tid; i < 48 * 256; i += 256) {
            int col = i % 48, slot = i / 48;
            int kk = slot >> 5, q = (slot >> 3) & 3, j = slot & 7;
            int h = kk * 32 + ((j < 4) ? (q * 4 + j) : (16 + q * 4 + (j - 4)));
            Wt_g[col * 264 + slot] = f2bf(W_kout[h * 48 + col]);
        }
        // whlo_g[h*8 + f] = bf16 hi of W_kin[f][h]; +4: lo residual
        {
            const int h = tid;
#pragma unroll
            for (int f = 0; f < 4; ++f) {
                float w = W_kin[f * 256 + h];
                ushort hi = f2bf(w);
                float lo = w - bf2f(hi);
                whlo_g[h * 8 + f] = hi;
                whlo_g[h * 8 + 4 + f] = f2bf(lo);
            }
        }
    }
}

// ---------------- Kernel B v11 (unchanged, measured ~262us) ----------------
__global__ __launch_bounds__(256, 3) void kB(
    const float* __restrict__ x,
    const float* __restrict__ stateK, const float* __restrict__ b_kout,
    const ushort* __restrict__ Wt_g, const ushort* __restrict__ whlo_g,
    const float* __restrict__ params,
    unsigned int* __restrict__ kmki, ushort* __restrict__ kevA,
    float2* __restrict__ pspl)
{
    __shared__ ushort Wt[48 * 264];    // 25,344 B
    __shared__ float  stS[16 * 260];   // 16,640 B
    __shared__ ushort whloS[2048];     //  4,096 B  [hidden][8: wh0..3, wl0..3]
    __shared__ float  geS[256];        //  1,024 B  [site_local*16 + h]
    __shared__ float  evS[4][5][16];   //  1,280 B  [wave][ti][site_local]
    const int tid = threadIdx.x;
    const int st = blockIdx.x & 127;   // site tile (0..127)
    const int tg = blockIdx.x >> 7;    // t group (0..49)
    const int s0 = st << 4;

    for (int i = tid; i < 3168; i += 256)
        ((uint2*)Wt)[i] = ((const uint2*)Wt_g)[i];
#pragma unroll
    for (int i = tid; i < 1024; i += 256) {
        int row = i >> 6, c = (i & 63) << 2;
        *(float4*)(stS + row * 260 + c) = *(const float4*)(stateK + (s0 + row) * 256 + c);
    }
    *(float4*)(whloS + tid * 8) = ((const float4*)whlo_g)[tid];
    geS[tid] = params[10 * 32768 + s0 * 16 + tid];
    __syncthreads();

    const int wv = tid >> 6, lane = tid & 63;
    const int mi = lane & 15, quad = lane >> 4;
    const int site = s0 + mi;
    const int t0 = tg * 20 + wv * 5;   // 50*20 = 1000, guard-free

    float xf[5][4];
#pragma unroll
    for (int ti = 0; ti < 5; ++ti) {
        const int t = t0 + ti;
        const int xb = (t * 2048 + site) * 6;
        float2 u23 = *(const float2*)(x + xb + 2);
        float2 u45 = *(const float2*)(x + xb + 4);
        xf[ti][0] = u23.x; xf[ti][1] = u23.y; xf[ti][2] = u45.x; xf[ti][3] = u45.y;
        if (lane < 16) {   // quad 0: ps/pl in [sg][t][sl] layout, ev tile in LDS
            float2 u01 = *(const float2*)(x + xb);
            float fl = fminf(fmaxf(u23.y * __builtin_amdgcn_rcpf(u23.y - u23.x + 1e-5f), 0.f), 1.f);
            const int sg = st * 4 + (mi >> 2), sl = mi & 3;
            pspl[(sg * 1000 + t) * 4 + sl] = make_float2(u01.x * (1.f - fl), u01.x * fl);
            evS[wv][ti][mi] = u01.y;
        }
    }

    unsigned int bfr[5][4];
#pragma unroll
    for (int ti = 0; ti < 5; ++ti) {
        const float x0 = xf[ti][0], x1 = xf[ti][1], x2 = xf[ti][2], x3 = xf[ti][3];
        unsigned int h01 = packbf2(x0, x1), h23 = packbf2(x2, x3);
        float l0 = x0 - bf2f((ushort)(h01 & 0xffffu));
        float l1 = x1 - bf2f((ushort)(h01 >> 16));
        float l2 = x2 - bf2f((ushort)(h23 & 0xffffu));
        float l3 = x3 - bf2f((ushort)(h23 >> 16));
        unsigned int l01 = packbf2(l0, l1), l23 = packbf2(l2, l3);
        bfr[ti][0] = (quad == 0) ? h01 : (quad == 1 ? l01 : 0u);
        bfr[ti][1] = (quad == 0) ? h23 : (quad == 1 ? l23 : 0u);
        bfr[ti][2] = (quad == 0) ? h01 : 0u;
        bfr[ti][3] = (quad == 0) ? h23 : 0u;
    }

    const float*  stp = stS + mi * 260;
    const ushort* Wt0 = Wt + mi * 264 + quad * 8;
    const int q4 = quad * 4;

    f32x4 acc[5][3];
#pragma unroll
    for (int ti = 0; ti < 5; ++ti)
#pragma unroll
        for (int j = 0; j < 3; ++j) acc[ti][j] = (f32x4){0.f, 0.f, 0.f, 0.f};

#pragma unroll 1
    for (int kk = 0; kk < 8; ++kk) {
        const int ko = kk * 32;
        union { short8 s; unsigned int u[4]; } W0, W1, A0, A1;
        W0.s = *(const short8*)(whloS + (ko + mi) * 8);
        W1.s = *(const short8*)(whloS + (ko + 16 + mi) * 8);
        A0.u[0] = (quad <= 1) ? W0.u[0] : 0u;
        A0.u[1] = (quad <= 1) ? W0.u[1] : 0u;
        A0.u[2] = (quad == 0) ? W0.u[2] : 0u;
        A0.u[3] = (quad == 0) ? W0.u[3] : 0u;
        A1.u[0] = (quad <= 1) ? W1.u[0] : 0u;
        A1.u[1] = (quad <= 1) ? W1.u[1] : 0u;
        A1.u[2] = (quad == 0) ? W1.u[2] : 0u;
        A1.u[3] = (quad == 0) ? W1.u[3] : 0u;
        f32x4 c0 = *(const f32x4*)(stp + ko + q4);
        f32x4 c1 = *(const f32x4*)(stp + ko + 16 + q4);
        short8 b0 = *(const short8*)(Wt0 + ko);
        short8 b1 = *(const short8*)(Wt0 + 16 * 264 + ko);
        short8 b2 = *(const short8*)(Wt0 + 32 * 264 + ko);
#pragma unroll
        for (int ti = 0; ti < 5; ++ti) {
            union { short8 s; unsigned int u[4]; } B;
            B.u[0] = bfr[ti][0]; B.u[1] = bfr[ti][1];
            B.u[2] = bfr[ti][2]; B.u[3] = bfr[ti][3];
            f32x4 z0 = __builtin_amdgcn_mfma_f32_16x16x32_bf16(A0.s, B.s, c0, 0, 0, 0);
            f32x4 z1 = __builtin_amdgcn_mfma_f32_16x16x32_bf16(A1.s, B.s, c1, 0, 0, 0);
            union { short8 s; unsigned int u[4]; } a;
            a.u[0] = packbf2(fast_tanh(z0[0]), fast_tanh(z0[1]));
            a.u[1] = packbf2(fast_tanh(z0[2]), fast_tanh(z0[3]));
            a.u[2] = packbf2(fast_tanh(z1[0]), fast_tanh(z1[1]));
            a.u[3] = packbf2(fast_tanh(z1[2]), fast_tanh(z1[3]));
            acc[ti][0] = __builtin_amdgcn_mfma_f32_16x16x32_bf16(a.s, b0, acc[ti][0], 0, 0, 0);
            acc[ti][1] = __builtin_amdgcn_mfma_f32_16x16x32_bf16(a.s, b1, acc[ti][1], 0, 0, 0);
            acc[ti][2] = __builtin_amdgcn_mfma_f32_16x16x32_bf16(a.s, b2, acc[ti][2], 0, 0, 0);
        }
    }

    // epilogue: kmki/kevA[site][t][h]
    const float bo0 = b_kout[mi], bo1 = b_kout[16 + mi], bo2 = b_kout[32 + mi];
#pragma unroll
    for (int ti = 0; ti < 5; ++ti) {
        const int t = t0 + ti;
#pragma unroll
        for (int reg = 0; reg < 4; ++reg) {
            const int sl = quad * 4 + reg;
            float km = __expf(acc[ti][0][reg] + bo0);
            float ki = fmaxf(acc[ti][1][reg] + bo1, 0.f);
            float ke = __expf(acc[ti][2][reg] + bo2);
            float kev = ke * evS[wv][ti][sl] * geS[sl * 16 + mi];
            const int idx = ((s0 + sl) * 1000 + t) * 16 + mi;
            kmki[idx] = (unsigned int)f2bf(km) | ((unsigned int)f2bf(ki) << 16);
            kevA[idx] = f2bf(kev);
        }
    }
}

// ---------------- Kernel C v14-DIAG: r6's v12 with REP=2 to surface counters ----------------
// DIAGNOSTIC ROUND (pre-committed in r6/r7): four structurally different kC variants
// all land at ~230us while issue/latency/BW models predict <=100us -> unmodeled
// mechanism. kC is idempotent (reads kmki/kevA/pspl/params, writes only yOut
// deterministically), so REP=2 doubles its dispatch time to ~460us -> it becomes the
// top dispatch in the rocprof table, exposing VALUBusy/Occupancy/FETCH/LDS_CONFLICT.
// Deliberate total regression ~519+230us this round; revert = delete the rep loop.
#define KM_STRIDE 4160   // 4096 + 64 pad
#define KE_BASE   16640  // 4*4160
#define KE_STRIDE 2080   // 2048 + 32 pad
#define PS_BASE   24960  // 16640 + 4*2080
#define BUF_SZ    27008  // 24960 + 2048
__global__ __launch_bounds__(64, 1) void kC(
    const unsigned int* __restrict__ kmki, const ushort* __restrict__ kevA,
    const float2* __restrict__ pspl,
    const float* __restrict__ params, float* __restrict__ yOut)
{
    __shared__ char lds[2 * BUF_SZ];   // 54,016 B
    const int tid = threadIdx.x;
    const int sg = blockIdx.x;              // s_group (4 sites per wave)
    const int sl = tid >> 4;
    const int s = sg * 4 + sl;
    const int h = tid & 15;
    const int gid = s * 16 + h;

    const float kp  = params[0 * 32768 + gid];
    const float ks_ = params[1 * 32768 + gid];
    const float kd  = params[2 * 32768 + gid];
    const float gd  = params[3 * 32768 + gid];
    const float gl  = params[4 * 32768 + gid];
    const float qbv = params[5 * 32768 + gid];
    const float gi  = params[6 * 32768 + gid];
    const float gi1 = params[7 * 32768 + gid];
    const float kd1 = params[8 * 32768 + gid];
    const float gd1 = params[9 * 32768 + gid];
    float wrga[8];
#pragma unroll
    for (int i = 0; i < 8; ++i) wrga[i] = params[(11 + i) * 32768 + gid];

    const char* kmG = (const char*)kmki;   // [site][t][h] uint   -> 64 B/t/site
    const char* keG = (const char*)kevA;   // [site][t][h] ushort -> 32 B/t/site
    const char* psG = (const char*)pspl;   // [sg][t][sl] float2  -> 32 B/t

#define STAGE(c, TAIL) do {                                                     \
        char* L = lds + ((c) & 1) * BUF_SZ;                                     \
        _Pragma("unroll")                                                       \
        for (int q = 0; q < 4; ++q) {                                           \
            const char* gk = kmG + ((size_t)(sg * 4 + q) * 1000 + (c) * 64) * 64; \
            const char* ge = keG + ((size_t)(sg * 4 + q) * 1000 + (c) * 64) * 32; \
            char* lk = L + q * KM_STRIDE;                                       \
            char* le = L + KE_BASE + q * KE_STRIDE;                             \
            if (!(TAIL)) {                                                      \
                _Pragma("unroll")                                               \
                for (int k = 0; k < 4; ++k) gll16(gk + k * 1024 + tid * 16, lk + k * 1024); \
                _Pragma("unroll")                                               \
                for (int k = 0; k < 2; ++k) gll16(ge + k * 1024 + tid * 16, le + k * 1024); \
            } else {                                                            \
                _Pragma("unroll")                                               \
                for (int k = 0; k < 2; ++k) gll16(gk + k * 1024 + tid * 16, lk + k * 1024); \
                _Pragma("unroll")                                               \
                for (int k = 0; k < 2; ++k) gll4(gk + 2048 + k * 256 + tid * 4, lk + 2048 + k * 256); \
                gll16(ge + tid * 16, le);                                       \
                gll4(ge + 1024 + tid * 4, le + 1024);                           \
            }                                                                   \
        }                                                                       \
        const char* gp = psG + ((size_t)sg * 1000 + (c) * 64) * 32;             \
        char* lp = L + PS_BASE;                                                 \
        if (!(TAIL)) { gll16(gp + tid * 16, lp); gll16(gp + 1024 + tid * 16, lp + 1024); } \
        else         { gll16(gp + tid * 16, lp); gll4(gp + 1024 + tid * 4, lp + 1024); }   \
    } while (0)

#define SCANB(c, sb) do {                                                       \
        const char* L = lds + ((c) & 1) * BUF_SZ;                               \
        const char* lk = L + sl * KM_STRIDE + h * 4 + (sb) * 512;               \
        const char* le = L + KE_BASE + sl * KE_STRIDE + h * 2 + (sb) * 256;     \
        const char* lp = L + PS_BASE + sl * 8 + (sb) * 256;                     \
        unsigned int a[8]; ushort e[8]; float2 p[8];                            \
        _Pragma("unroll")                                                       \
        for (int i = 0; i < 8; ++i) {                                           \
            a[i] = *(const unsigned int*)(lk + i * 64);                         \
            e[i] = *(const ushort*)(le + i * 32);                               \
            p[i] = *(const float2*)(lp + i * 32);                               \
        }                                                                       \
        _Pragma("unroll")                                                       \
        for (int i = 0; i < 8; ++i) {                                           \
            float km = __builtin_bit_cast(float, a[i] << 16);                   \
            float ki = __builtin_bit_cast(float, a[i] & 0xffff0000u);           \
            float kev = __builtin_bit_cast(float, ((unsigned int)e[i]) << 16);  \
            float ps = p[i].x, pl = p[i].y;                                     \
            Sf += ps;                                                           \
            float qf = fminf(Sf, km); Sf -= qf;                                 \
            float inflow = qf + pl;                                             \
            float qd = inflow * gi;                                             \
            Ss = fmaf(inflow, gi1, Ss);                                         \
            float E = fminf(Ss, kev); Ss -= E;                                  \
            float qi = fminf(ki, Ss); Ss -= qi;                                 \
            float qp = kp * fmaxf(Ss - gl, 0.f);                                \
            float qsa = ks_ * fminf(Ss, gl);                                    \
            Ss -= qp + qsa;                                                     \
            Sg = fmaf(qsa, gd, Sg);                                             \
            float qg = fmaf(kd, Sg, qbv);                                       \
            Sg *= kd1;                                                          \
            qcur[i] = fmaf(qsa, gd1, qp) + qg + qd + qi;                        \
        }                                                                       \
    } while (0)

#define CONV_STORE(m) do {                                                      \
        float z[8];                                                             \
        _Pragma("unroll")                                                       \
        for (int i = 0; i < 8; ++i) {                                           \
            float za = wrga[6] * ((i >= 6) ? qp1[i - 6] : qp2[i + 2]);          \
            za = fmaf(wrga[4], (i >= 4) ? qp1[i - 4] : qp2[i + 4], za);         \
            za = fmaf(wrga[2], (i >= 2) ? qp1[i - 2] : qp2[i + 6], za);         \
            za = fmaf(wrga[0], qp1[i], za);                                     \
            float zb = wrga[7] * ((i >= 7) ? qp1[i - 7] : qp2[i + 1]);          \
            zb = fmaf(wrga[5], (i >= 5) ? qp1[i - 5] : qp2[i + 3], zb);         \
            zb = fmaf(wrga[3], (i >= 3) ? qp1[i - 3] : qp2[i + 5], zb);         \
            zb = fmaf(wrga[1], (i >= 1) ? qp1[i - 1] : qp2[i + 7], zb);         \
            z[i] = za + zb;                                                     \
        }                                                                       \
        _Pragma("unroll")                                                       \
        for (int i = 0; i < 8; ++i) z[i] = dpp_add<0xB1>(z[i]);                 \
        _Pragma("unroll")                                                       \
        for (int i = 0; i < 8; ++i) z[i] = dpp_add<0x4E>(z[i]);                 \
        _Pragma("unroll")                                                       \
        for (int i = 0; i < 8; ++i) z[i] = dpp_add<0x141>(z[i]);                \
        _Pragma("unroll")                                                       \
        for (int i = 0; i < 8; ++i) z[i] = dpp_add<0x140>(z[i]);                \
        if (h == 0) {                                                           \
            _Pragma("unroll")                                                   \
            for (int i = 0; i < 8; ++i) {                                       \
                const int t = (m) * 8 + i;                                      \
                if (t >= 7) yOut[(t - 7) * 2048 + s] = z[i];                    \
            }                                                                   \
        }                                                                       \
    } while (0)

#pragma unroll 1
    for (int rep = 0; rep < 2; ++rep) {
        float Sf = 0.f, Ss = 0.f, Sg = 0.f;
        float qcur[8], qp1[8], qp2[8];
#pragma unroll
        for (int i = 0; i < 8; ++i) { qcur[i] = 0.f; qp1[i] = 0.f; qp2[i] = 0.f; }

        STAGE(0, false);
        int g = 0;
#pragma unroll 1
        for (int c = 0; c < 16; ++c) {
            if (c < 15) {
                if (c + 1 == 15) STAGE(15, true);
                else             STAGE(c + 1, false);
                asm volatile("s_waitcnt vmcnt(26)" ::: "memory");
            } else {
                asm volatile("s_waitcnt vmcnt(0)" ::: "memory");
            }
            const int NSB = (c == 15) ? 5 : 8;
#pragma unroll 1
            for (int sb = 0; sb < NSB; ++sb, ++g) {
                SCANB(c, sb);
                CONV_STORE(g - 1);
#pragma unroll
                for (int i = 0; i < 8; ++i) { qp2[i] = qp1[i]; qp1[i] = qcur[i]; }
            }
            asm volatile("" ::: "memory");
        }
        CONV_STORE(124);
    }
#undef STAGE
#undef SCANB
#undef CONV_STORE
}

// ---------------- launch ----------------
extern "C" void kernel_launch(void* const* d_in, const int* in_sizes, int n_in,
                              void* d_out, int out_size, void* d_ws, size_t ws_size,
                              hipStream_t stream) {
    const float* x      = (const float*)d_in[0];
    const float* xc     = (const float*)d_in[1];
    const float* W_fc   = (const float*)d_in[2];
    const float* b_fc   = (const float*)d_in[3];
    const float* W_r    = (const float*)d_in[4];
    const float* b_r    = (const float*)d_in[5];
    const float* W_g    = (const float*)d_in[6];
    const float* b_g    = (const float*)d_in[7];
    const float* W_kin  = (const float*)d_in[8];
    const float* b_kin  = (const float*)d_in[9];
    const float* W_kout = (const float*)d_in[10];
    const float* b_kout = (const float*)d_in[11];
    float* yOut = (float*)d_out;

    char* ws = (char*)d_ws;
    float*  stateK = (float*)(ws + 0);                        // 2 MB
    float*  params = (float*)(ws + (2 << 20));                // 19 planes (reserve 4 MB)
    ushort* Wt_g   = (ushort*)(ws + (6 << 20));               // 25,344 B
    ushort* whlo_g = (ushort*)(ws + (6 << 20) + (64 << 10));  // 4,096 B
    char*   p      = ws + (6 << 20) + (128 << 10);
    float2* pspl   = (float2*)p;                              // 16,384,000 B
    unsigned int* kmki = (unsigned int*)(p + 16384000);       // 131,072,000 B
    ushort* kevA   = (ushort*)(p + 16384000 + 131072000);     //  65,536,000 B

    hipLaunchKernelGGL(kA, dim3(2048), dim3(256), 0, stream,
                       xc, W_fc, b_fc, W_r, b_r, W_g, b_g, W_kin, b_kin, W_kout,
                       stateK, params, Wt_g, whlo_g);
    hipLaunchKernelGGL(kB, dim3(128 * 50), dim3(256), 0, stream,
                       x, stateK, b_kout, Wt_g, whlo_g, params, kmki, kevA, pspl);
    hipLaunchKernelGGL(kC, dim3(512), dim3(64), 0, stream,
                       kmki, kevA, pspl, params, yOut);
}

// Round 9
// 479.058 us; speedup vs baseline: 1.3213x; 1.3213x over previous
//
#include <hip/hip_runtime.h>
#include <hip/hip_bf16.h>

// Problem constants
#define NT   1000
#define NS   2048
#define NH   16
#define NR   8
#define HS   256
#define TOUT 993   // NT - NR + 1

typedef __attribute__((ext_vector_type(8))) short short8;
typedef __attribute__((ext_vector_type(4))) float f32x4;

__device__ __forceinline__ ushort f2bf(float f) {
    union { float f; unsigned int u; } v; v.f = f;
    unsigned int u = v.u;
    return (ushort)((u + 0x7fffu + ((u >> 16) & 1u)) >> 16);
}
__device__ __forceinline__ float bf2f(ushort u) {
    union { unsigned int i; float f; } v; v.i = ((unsigned int)u) << 16; return v.f;
}
__device__ __forceinline__ unsigned int packbf2(float lo, float hi) {
    union { __hip_bfloat162 b; unsigned int u; } v;
    v.b = __float22bfloat162_rn(make_float2(lo, hi));
    return v.u;
}
__device__ __forceinline__ float sigf(float x) { return 1.f / (1.f + __expf(-x)); }
__device__ __forceinline__ float fast_tanh(float z) {
    float e = exp2f(z * 2.885390082f);
    return 1.f - 2.f * __builtin_amdgcn_rcpf(e + 1.f);
}
template<int CTRL>
__device__ __forceinline__ float dpp_add(float v) {
    int s = __builtin_amdgcn_update_dpp(0, __builtin_bit_cast(int, v), CTRL, 0xf, 0xf, true);
    return v + __builtin_bit_cast(float, s);
}
// async global->LDS DMA: zero result VGPRs, counted by vmcnt.
__device__ __forceinline__ void gll16(const void* g, void* l) {
    __builtin_amdgcn_global_load_lds((const __attribute__((address_space(1))) unsigned int*)g,
                                     (__attribute__((address_space(3))) unsigned int*)l, 16, 0, 0);
}
__device__ __forceinline__ void gll4(const void* g, void* l) {
    __builtin_amdgcn_global_load_lds((const __attribute__((address_space(1))) unsigned int*)g,
                                     (__attribute__((address_space(3))) unsigned int*)l, 4, 0, 0);
}

// params planes: 0 kp, 1 ks, 2 kd, 3 gd, 4 gl, 5 qb, 6 gi, 7 1-gi, 8 1-kd,
//                9 1-gd, 10 ge, 11..18 wrga

// ---------------- Kernel Aw: weight prep ----------------
// r8 diagnosis: kC is only ~114us (rep=2 added exactly 114); the missing ~143us is
// kA+overhead. Old kA: 2048 blocks each re-read full W_g+W_r (294KB, 602MB L2 total)
// through a 256-deep serial FMA chain with L2-latency links. Rewrite as MFMA GEMM.
// kAw emits WA fragments: bf16 hi/lo of W = [W_g | W_r] (256k x 288cols) in
// fragment-ready layout WA[ct][kc][lane][8]: lane=(q*16+m), col=ct*16+m,
// k=kc*32+q*8+j  ->  one b128 load per A-fragment in kA2.
__global__ __launch_bounds__(256) void kAw(
    const float* __restrict__ W_g, const float* __restrict__ W_r,
    const float* __restrict__ W_kin, const float* __restrict__ W_kout,
    ushort* __restrict__ WAhi, ushort* __restrict__ WAlo,
    ushort* __restrict__ Wt_g, ushort* __restrict__ whlo_g)
{
    const int tid = threadIdx.x, b = blockIdx.x;   // 288 blocks x 256 = 73728 elements
    const int idx = b * 256 + tid;
    const int j = idx & 7, lane = (idx >> 3) & 63, chunk = idx >> 9;
    const int kc = chunk & 7, ct = chunk >> 3;
    const int col = ct * 16 + (lane & 15);
    const int k = kc * 32 + (lane >> 4) * 8 + j;
    const float* W = (col < 144) ? W_g : W_r;
    const int c2 = (col < 144) ? col : col - 144;
    const float w = W[k * 144 + c2];
    const ushort hi = f2bf(w);
    WAhi[idx] = hi;
    WAlo[idx] = f2bf(w - bf2f(hi));

    if (b == 0) {
        // Wt_g: W_kout^T bf16, stride 264, rows permuted to the first-MFMA D layout (kB).
        for (int i = tid; i < 48 * 256; i += 256) {
            int c = i % 48, slot = i / 48;
            int kk2 = slot >> 5, q = (slot >> 3) & 3, jj = slot & 7;
            int h = kk2 * 32 + ((jj < 4) ? (q * 4 + jj) : (16 + q * 4 + (jj - 4)));
            Wt_g[c * 264 + slot] = f2bf(W_kout[h * 48 + c]);
        }
        const int h = tid;
#pragma unroll
        for (int f = 0; f < 4; ++f) {
            float w2 = W_kin[f * 256 + h];
            ushort hi2 = f2bf(w2);
            whlo_g[h * 8 + f] = hi2;
            whlo_g[h * 8 + 4 + f] = f2bf(w2 - bf2f(hi2));
        }
    }
}

// ---------------- Kernel A1: state + hG (phase 1 only) ----------------
__global__ __launch_bounds__(256) void kA1(
    const float* __restrict__ xc, const float* __restrict__ W_fc,
    const float* __restrict__ b_fc, const float* __restrict__ b_kin,
    float* __restrict__ stateK, ushort* __restrict__ hGh, ushort* __restrict__ hGl)
{
    __shared__ float xcs[32];
    const int s = blockIdx.x, tid = threadIdx.x;
    if (tid < 32) xcs[tid] = xc[s * 32 + tid];
    __syncthreads();
    float acc = b_fc[tid];
#pragma unroll 8
    for (int k = 0; k < 32; ++k) acc = fmaf(xcs[k], W_fc[k * 256 + tid], acc);
    stateK[s * 256 + tid] = acc + b_kin[tid];
    float hg = tanhf(acc);
    ushort hi = f2bf(hg);
    hGh[s * 256 + tid] = hi;
    hGl[s * 256 + tid] = f2bf(hg - bf2f(hi));
}

// ---------------- Kernel A2: pGR GEMM via MFMA + step-5 epilogue ----------------
// 128 blocks x 256 thr; block = 16 sites. pGR[16x288] = hG[16x256] @ W[256x288]
// with hi/lo 3-term MFMA (wh*hh + wl*hh + wh*hl). Wave w does col-tiles w,w+4,...
// D layout (m89): col=lane&15=site(n), row=4q+reg=col-in-tile(m). Then step 5
// (sigmoids/softmaxes/params) with 256 threads = 16 sites x 16 heads in-block.
__global__ __launch_bounds__(256) void kA2(
    const ushort* __restrict__ hGh, const ushort* __restrict__ hGl,
    const ushort* __restrict__ WAhi, const ushort* __restrict__ WAlo,
    const float* __restrict__ b_g, const float* __restrict__ b_r,
    float* __restrict__ params)
{
    __shared__ ushort hGhS[16][264];   // pad 8 bf16: site-stride 528B -> 4-bank offset
    __shared__ ushort hGlS[16][264];
    __shared__ float  pGRS[16][292];
    const int tid = threadIdx.x;
    const int s0 = blockIdx.x * 16;

    for (int i = tid; i < 512; i += 256) {             // 16 sites * 32 chunks of 8 bf16
        int site = i >> 5, off = (i & 31) * 8;
        *(uint4*)&hGhS[site][off] = *(const uint4*)&hGh[(s0 + site) * 256 + off];
        *(uint4*)&hGlS[site][off] = *(const uint4*)&hGl[(s0 + site) * 256 + off];
    }
    __syncthreads();

    const int wv = tid >> 6, lane = tid & 63;
    const int n = lane & 15, q = lane >> 4;
    for (int ct = wv; ct < 18; ct += 4) {
        f32x4 acc = (f32x4){0.f, 0.f, 0.f, 0.f};
#pragma unroll
        for (int kc = 0; kc < 8; ++kc) {
            const int fidx = ((ct * 8 + kc) * 64 + lane) * 8;
            short8 awh = *(const short8*)(WAhi + fidx);
            short8 awl = *(const short8*)(WAlo + fidx);
            short8 bhh = *(const short8*)&hGhS[n][kc * 32 + q * 8];
            short8 bhl = *(const short8*)&hGlS[n][kc * 32 + q * 8];
            acc = __builtin_amdgcn_mfma_f32_16x16x32_bf16(awh, bhh, acc, 0, 0, 0);
            acc = __builtin_amdgcn_mfma_f32_16x16x32_bf16(awl, bhh, acc, 0, 0, 0);
            acc = __builtin_amdgcn_mfma_f32_16x16x32_bf16(awh, bhl, acc, 0, 0, 0);
        }
#pragma unroll
        for (int r = 0; r < 4; ++r) pGRS[n][ct * 16 + q * 4 + r] = acc[r];
    }
    __syncthreads();

    // step 5: thread = (site sl, head h)
    const int sl = tid >> 4, h = tid & 15;
    const int s = s0 + sl;
    float g0 = pGRS[sl][0 * 16 + h] + b_g[0 * 16 + h];
    float g1 = pGRS[sl][1 * 16 + h] + b_g[1 * 16 + h];
    float g2 = pGRS[sl][2 * 16 + h] + b_g[2 * 16 + h];
    float g3 = pGRS[sl][3 * 16 + h] + b_g[3 * 16 + h];
    float g4 = pGRS[sl][4 * 16 + h] + b_g[4 * 16 + h];
    float g5 = pGRS[sl][5 * 16 + h] + b_g[5 * 16 + h];
    float g6 = pGRS[sl][6 * 16 + h] + b_g[6 * 16 + h];
    float g7 = pGRS[sl][7 * 16 + h] + b_g[7 * 16 + h];
    float g8 = pGRS[sl][8 * 16 + h] + b_g[8 * 16 + h];
    float kp = sigf(g0), ksg = sigf(g1), kd = sigf(g2), gd = sigf(g3);
    float t4 = sigf(g4) * 10.f; float gl = t4 * t4 * t4;
    float qb = fmaxf(g5, 0.f) * 0.1f;
    float gi = fminf(fmaxf(g7 * (1.f / 6.f) + 0.5f, 0.f), 1.f) * 0.5f;
    float ge = fmaxf(g8, 0.f);
    float m = g6;
    for (int o = 1; o < 16; o <<= 1) m = fmaxf(m, __shfl_xor(m, o));
    float e = __expf(g6 - m), esum = e;
    for (int o = 1; o < 16; o <<= 1) esum += __shfl_xor(esum, o);
    float ga = e / esum;
    float r9[9], rm = -1e30f;
#pragma unroll
    for (int i = 0; i < 9; ++i) {
        r9[i] = pGRS[sl][144 + h * 9 + i] + b_r[h * 9 + i];
        rm = fmaxf(rm, r9[i]);
    }
    float er[9], es = 0.f;
#pragma unroll
    for (int i = 0; i < 9; ++i) { er[i] = __expf(r9[i] - rm); es += er[i]; }
    float inv_es = 1.f / es, c = 0.f, wsum = 0.f, w[8];
#pragma unroll
    for (int i = 0; i < 8; ++i) {
        float si = er[i] * inv_es; c += si;
        float wi = fminf(c, 1.f - c + si);
        w[i] = wi; wsum += wi;
    }
    const int base = s * 16 + h;
    params[0 * 32768 + base] = kp;       params[1 * 32768 + base] = ksg;
    params[2 * 32768 + base] = kd;       params[3 * 32768 + base] = gd;
    params[4 * 32768 + base] = gl;       params[5 * 32768 + base] = qb;
    params[6 * 32768 + base] = gi;       params[7 * 32768 + base] = 1.f - gi;
    params[8 * 32768 + base] = 1.f - kd; params[9 * 32768 + base] = 1.f - gd;
    params[10 * 32768 + base] = ge;
    float sc = ga / wsum;
#pragma unroll
    for (int i = 0; i < 8; ++i) params[(11 + i) * 32768 + base] = w[i] * sc;
}

// ---------------- Kernel B v11 (unchanged, measured ~262us) ----------------
__global__ __launch_bounds__(256, 3) void kB(
    const float* __restrict__ x,
    const float* __restrict__ stateK, const float* __restrict__ b_kout,
    const ushort* __restrict__ Wt_g, const ushort* __restrict__ whlo_g,
    const float* __restrict__ params,
    unsigned int* __restrict__ kmki, ushort* __restrict__ kevA,
    float2* __restrict__ pspl)
{
    __shared__ ushort Wt[48 * 264];    // 25,344 B
    __shared__ float  stS[16 * 260];   // 16,640 B
    __shared__ ushort whloS[2048];     //  4,096 B  [hidden][8: wh0..3, wl0..3]
    __shared__ float  geS[256];        //  1,024 B  [site_local*16 + h]
    __shared__ float  evS[4][5][16];   //  1,280 B  [wave][ti][site_local]
    const int tid = threadIdx.x;
    const int st = blockIdx.x & 127;   // site tile (0..127)
    const int tg = blockIdx.x >> 7;    // t group (0..49)
    const int s0 = st << 4;

    for (int i = tid; i < 3168; i += 256)
        ((uint2*)Wt)[i] = ((const uint2*)Wt_g)[i];
#pragma unroll
    for (int i = tid; i < 1024; i += 256) {
        int row = i >> 6, c = (i & 63) << 2;
        *(float4*)(stS + row * 260 + c) = *(const float4*)(stateK + (s0 + row) * 256 + c);
    }
    *(float4*)(whloS + tid * 8) = ((const float4*)whlo_g)[tid];
    geS[tid] = params[10 * 32768 + s0 * 16 + tid];
    __syncthreads();

    const int wv = tid >> 6, lane = tid & 63;
    const int mi = lane & 15, quad = lane >> 4;
    const int site = s0 + mi;
    const int t0 = tg * 20 + wv * 5;   // 50*20 = 1000, guard-free

    float xf[5][4];
#pragma unroll
    for (int ti = 0; ti < 5; ++ti) {
        const int t = t0 + ti;
        const int xb = (t * 2048 + site) * 6;
        float2 u23 = *(const float2*)(x + xb + 2);
        float2 u45 = *(const float2*)(x + xb + 4);
        xf[ti][0] = u23.x; xf[ti][1] = u23.y; xf[ti][2] = u45.x; xf[ti][3] = u45.y;
        if (lane < 16) {   // quad 0: ps/pl in [sg][t][sl] layout, ev tile in LDS
            float2 u01 = *(const float2*)(x + xb);
            float fl = fminf(fmaxf(u23.y * __builtin_amdgcn_rcpf(u23.y - u23.x + 1e-5f), 0.f), 1.f);
            const int sg = st * 4 + (mi >> 2), sl = mi & 3;
            pspl[(sg * 1000 + t) * 4 + sl] = make_float2(u01.x * (1.f - fl), u01.x * fl);
            evS[wv][ti][mi] = u01.y;
        }
    }

    unsigned int bfr[5][4];
#pragma unroll
    for (int ti = 0; ti < 5; ++ti) {
        const float x0 = xf[ti][0], x1 = xf[ti][1], x2 = xf[ti][2], x3 = xf[ti][3];
        unsigned int h01 = packbf2(x0, x1), h23 = packbf2(x2, x3);
        float l0 = x0 - bf2f((ushort)(h01 & 0xffffu));
        float l1 = x1 - bf2f((ushort)(h01 >> 16));
        float l2 = x2 - bf2f((ushort)(h23 & 0xffffu));
        float l3 = x3 - bf2f((ushort)(h23 >> 16));
        unsigned int l01 = packbf2(l0, l1), l23 = packbf2(l2, l3);
        bfr[ti][0] = (quad == 0) ? h01 : (quad == 1 ? l01 : 0u);
        bfr[ti][1] = (quad == 0) ? h23 : (quad == 1 ? l23 : 0u);
        bfr[ti][2] = (quad == 0) ? h01 : 0u;
        bfr[ti][3] = (quad == 0) ? h23 : 0u;
    }

    const float*  stp = stS + mi * 260;
    const ushort* Wt0 = Wt + mi * 264 + quad * 8;
    const int q4 = quad * 4;

    f32x4 acc[5][3];
#pragma unroll
    for (int ti = 0; ti < 5; ++ti)
#pragma unroll
        for (int j = 0; j < 3; ++j) acc[ti][j] = (f32x4){0.f, 0.f, 0.f, 0.f};

#pragma unroll 1
    for (int kk = 0; kk < 8; ++kk) {
        const int ko = kk * 32;
        union { short8 s; unsigned int u[4]; } W0, W1, A0, A1;
        W0.s = *(const short8*)(whloS + (ko + mi) * 8);
        W1.s = *(const short8*)(whloS + (ko + 16 + mi) * 8);
        A0.u[0] = (quad <= 1) ? W0.u[0] : 0u;
        A0.u[1] = (quad <= 1) ? W0.u[1] : 0u;
        A0.u[2] = (quad == 0) ? W0.u[2] : 0u;
        A0.u[3] = (quad == 0) ? W0.u[3] : 0u;
        A1.u[0] = (quad <= 1) ? W1.u[0] : 0u;
        A1.u[1] = (quad <= 1) ? W1.u[1] : 0u;
        A1.u[2] = (quad == 0) ? W1.u[2] : 0u;
        A1.u[3] = (quad == 0) ? W1.u[3] : 0u;
        f32x4 c0 = *(const f32x4*)(stp + ko + q4);
        f32x4 c1 = *(const f32x4*)(stp + ko + 16 + q4);
        short8 b0 = *(const short8*)(Wt0 + ko);
        short8 b1 = *(const short8*)(Wt0 + 16 * 264 + ko);
        short8 b2 = *(const short8*)(Wt0 + 32 * 264 + ko);
#pragma unroll
        for (int ti = 0; ti < 5; ++ti) {
            union { short8 s; unsigned int u[4]; } B;
            B.u[0] = bfr[ti][0]; B.u[1] = bfr[ti][1];
            B.u[2] = bfr[ti][2]; B.u[3] = bfr[ti][3];
            f32x4 z0 = __builtin_amdgcn_mfma_f32_16x16x32_bf16(A0.s, B.s, c0, 0, 0, 0);
            f32x4 z1 = __builtin_amdgcn_mfma_f32_16x16x32_bf16(A1.s, B.s, c1, 0, 0, 0);
            union { short8 s; unsigned int u[4]; } a;
            a.u[0] = packbf2(fast_tanh(z0[0]), fast_tanh(z0[1]));
            a.u[1] = packbf2(fast_tanh(z0[2]), fast_tanh(z0[3]));
            a.u[2] = packbf2(fast_tanh(z1[0]), fast_tanh(z1[1]));
            a.u[3] = packbf2(fast_tanh(z1[2]), fast_tanh(z1[3]));
            acc[ti][0] = __builtin_amdgcn_mfma_f32_16x16x32_bf16(a.s, b0, acc[ti][0], 0, 0, 0);
            acc[ti][1] = __builtin_amdgcn_mfma_f32_16x16x32_bf16(a.s, b1, acc[ti][1], 0, 0, 0);
            acc[ti][2] = __builtin_amdgcn_mfma_f32_16x16x32_bf16(a.s, b2, acc[ti][2], 0, 0, 0);
        }
    }

    // epilogue: kmki/kevA[site][t][h]
    const float bo0 = b_kout[mi], bo1 = b_kout[16 + mi], bo2 = b_kout[32 + mi];
#pragma unroll
    for (int ti = 0; ti < 5; ++ti) {
        const int t = t0 + ti;
#pragma unroll
        for (int reg = 0; reg < 4; ++reg) {
            const int sl = quad * 4 + reg;
            float km = __expf(acc[ti][0][reg] + bo0);
            float ki = fmaxf(acc[ti][1][reg] + bo1, 0.f);
            float ke = __expf(acc[ti][2][reg] + bo2);
            float kev = ke * evS[wv][ti][sl] * geS[sl * 16 + mi];
            const int idx = ((s0 + sl) * 1000 + t) * 16 + mi;
            kmki[idx] = (unsigned int)f2bf(km) | ((unsigned int)f2bf(ki) << 16);
            kevA[idx] = f2bf(kev);
        }
    }
}

// ---------------- Kernel C v12 (r6 config, measured ~114us net) ----------------
#define KM_STRIDE 4160   // 4096 + 64 pad
#define KE_BASE   16640  // 4*4160
#define KE_STRIDE 2080   // 2048 + 32 pad
#define PS_BASE   24960  // 16640 + 4*2080
#define BUF_SZ    27008  // 24960 + 2048
__global__ __launch_bounds__(64, 1) void kC(
    const unsigned int* __restrict__ kmki, const ushort* __restrict__ kevA,
    const float2* __restrict__ pspl,
    const float* __restrict__ params, float* __restrict__ yOut)
{
    __shared__ char lds[2 * BUF_SZ];   // 54,016 B
    const int tid = threadIdx.x;
    const int sg = blockIdx.x;              // s_group (4 sites per wave)
    const int sl = tid >> 4;
    const int s = sg * 4 + sl;
    const int h = tid & 15;
    const int gid = s * 16 + h;

    const float kp  = params[0 * 32768 + gid];
    const float ks_ = params[1 * 32768 + gid];
    const float kd  = params[2 * 32768 + gid];
    const float gd  = params[3 * 32768 + gid];
    const float gl  = params[4 * 32768 + gid];
    const float qbv = params[5 * 32768 + gid];
    const float gi  = params[6 * 32768 + gid];
    const float gi1 = params[7 * 32768 + gid];
    const float kd1 = params[8 * 32768 + gid];
    const float gd1 = params[9 * 32768 + gid];
    float wrga[8];
#pragma unroll
    for (int i = 0; i < 8; ++i) wrga[i] = params[(11 + i) * 32768 + gid];

    float Sf = 0.f, Ss = 0.f, Sg = 0.f;
    float qcur[8], qp1[8], qp2[8];
#pragma unroll
    for (int i = 0; i < 8; ++i) { qcur[i] = 0.f; qp1[i] = 0.f; qp2[i] = 0.f; }

    const char* kmG = (const char*)kmki;   // [site][t][h] uint   -> 64 B/t/site
    const char* keG = (const char*)kevA;   // [site][t][h] ushort -> 32 B/t/site
    const char* psG = (const char*)pspl;   // [sg][t][sl] float2  -> 32 B/t

#define STAGE(c, TAIL) do {                                                     \
        char* L = lds + ((c) & 1) * BUF_SZ;                                     \
        _Pragma("unroll")                                                       \
        for (int q = 0; q < 4; ++q) {                                           \
            const char* gk = kmG + ((size_t)(sg * 4 + q) * 1000 + (c) * 64) * 64; \
            const char* ge = keG + ((size_t)(sg * 4 + q) * 1000 + (c) * 64) * 32; \
            char* lk = L + q * KM_STRIDE;                                       \
            char* le = L + KE_BASE + q * KE_STRIDE;                             \
            if (!(TAIL)) {                                                      \
                _Pragma("unroll")                                               \
                for (int k = 0; k < 4; ++k) gll16(gk + k * 1024 + tid * 16, lk + k * 1024); \
                _Pragma("unroll")                                               \
                for (int k = 0; k < 2; ++k) gll16(ge + k * 1024 + tid * 16, le + k * 1024); \
            } else {                                                            \
                _Pragma("unroll")                                               \
                for (int k = 0; k < 2; ++k) gll16(gk + k * 1024 + tid * 16, lk + k * 1024); \
                _Pragma("unroll")                                               \
                for (int k = 0; k < 2; ++k) gll4(gk + 2048 + k * 256 + tid * 4, lk + 2048 + k * 256); \
                gll16(ge + tid * 16, le);                                       \
                gll4(ge + 1024 + tid * 4, le + 1024);                           \
            }                                                                   \
        }                                                                       \
        const char* gp = psG + ((size_t)sg * 1000 + (c) * 64) * 32;             \
        char* lp = L + PS_BASE;                                                 \
        if (!(TAIL)) { gll16(gp + tid * 16, lp); gll16(gp + 1024 + tid * 16, lp + 1024); } \
        else         { gll16(gp + tid * 16, lp); gll4(gp + 1024 + tid * 4, lp + 1024); }   \
    } while (0)

#define SCANB(c, sb) do {                                                       \
        const char* L = lds + ((c) & 1) * BUF_SZ;                               \
        const char* lk = L + sl * KM_STRIDE + h * 4 + (sb) * 512;               \
        const char* le = L + KE_BASE + sl * KE_STRIDE + h * 2 + (sb) * 256;     \
        const char* lp = L + PS_BASE + sl * 8 + (sb) * 256;                     \
        unsigned int a[8]; ushort e[8]; float2 p[8];                            \
        _Pragma("unroll")                                                       \
        for (int i = 0; i < 8; ++i) {                                           \
            a[i] = *(const unsigned int*)(lk + i * 64);                         \
            e[i] = *(const ushort*)(le + i * 32);                               \
            p[i] = *(const float2*)(lp + i * 32);                               \
        }                                                                       \
        _Pragma("unroll")                                                       \
        for (int i = 0; i < 8; ++i) {                                           \
            float km = __builtin_bit_cast(float, a[i] << 16);                   \
            float ki = __builtin_bit_cast(float, a[i] & 0xffff0000u);           \
            float kev = __builtin_bit_cast(float, ((unsigned int)e[i]) << 16);  \
            float ps = p[i].x, pl = p[i].y;                                     \
            Sf += ps;                                                           \
            float qf = fminf(Sf, km); Sf -= qf;                                 \
            float inflow = qf + pl;                                             \
            float qd = inflow * gi;                                             \
            Ss = fmaf(inflow, gi1, Ss);                                         \
            float E = fminf(Ss, kev); Ss -= E;                                  \
            float qi = fminf(ki, Ss); Ss -= qi;                                 \
            float qp = kp * fmaxf(Ss - gl, 0.f);                                \
            float qsa = ks_ * fminf(Ss, gl);                                    \
            Ss -= qp + qsa;                                                     \
            Sg = fmaf(qsa, gd, Sg);                                             \
            float qg = fmaf(kd, Sg, qbv);                                       \
            Sg *= kd1;                                                          \
            qcur[i] = fmaf(qsa, gd1, qp) + qg + qd + qi;                        \
        }                                                                       \
    } while (0)

#define CONV_STORE(m) do {                                                      \
        float z[8];                                                             \
        _Pragma("unroll")                                                       \
        for (int i = 0; i < 8; ++i) {                                           \
            float za = wrga[6] * ((i >= 6) ? qp1[i - 6] : qp2[i + 2]);          \
            za = fmaf(wrga[4], (i >= 4) ? qp1[i - 4] : qp2[i + 4], za);         \
            za = fmaf(wrga[2], (i >= 2) ? qp1[i - 2] : qp2[i + 6], za);         \
            za = fmaf(wrga[0], qp1[i], za);                                     \
            float zb = wrga[7] * ((i >= 7) ? qp1[i - 7] : qp2[i + 1]);          \
            zb = fmaf(wrga[5], (i >= 5) ? qp1[i - 5] : qp2[i + 3], zb);         \
            zb = fmaf(wrga[3], (i >= 3) ? qp1[i - 3] : qp2[i + 5], zb);         \
            zb = fmaf(wrga[1], (i >= 1) ? qp1[i - 1] : qp2[i + 7], zb);         \
            z[i] = za + zb;                                                     \
        }                                                                       \
        _Pragma("unroll")                                                       \
        for (int i = 0; i < 8; ++i) z[i] = dpp_add<0xB1>(z[i]);                 \
        _Pragma("unroll")                                                       \
        for (int i = 0; i < 8; ++i) z[i] = dpp_add<0x4E>(z[i]);                 \
        _Pragma("unroll")                                                       \
        for (int i = 0; i < 8; ++i) z[i] = dpp_add<0x141>(z[i]);                \
        _Pragma("unroll")                                                       \
        for (int i = 0; i < 8; ++i) z[i] = dpp_add<0x140>(z[i]);                \
        if (h == 0) {                                                           \
            _Pragma("unroll")                                                   \
            for (int i = 0; i < 8; ++i) {                                       \
                const int t = (m) * 8 + i;                                      \
                if (t >= 7) yOut[(t - 7) * 2048 + s] = z[i];                    \
            }                                                                   \
        }                                                                       \
    } while (0)

    STAGE(0, false);
    int g = 0;
#pragma unroll 1
    for (int c = 0; c < 16; ++c) {
        if (c < 15) {
            if (c + 1 == 15) STAGE(15, true);
            else             STAGE(c + 1, false);
            asm volatile("s_waitcnt vmcnt(26)" ::: "memory");
        } else {
            asm volatile("s_waitcnt vmcnt(0)" ::: "memory");
        }
        const int NSB = (c == 15) ? 5 : 8;
#pragma unroll 1
        for (int sb = 0; sb < NSB; ++sb, ++g) {
            SCANB(c, sb);
            CONV_STORE(g - 1);
#pragma unroll
            for (int i = 0; i < 8; ++i) { qp2[i] = qp1[i]; qp1[i] = qcur[i]; }
        }
        asm volatile("" ::: "memory");
    }
    CONV_STORE(124);
#undef STAGE
#undef SCANB
#undef CONV_STORE
}

// ---------------- launch ----------------
extern "C" void kernel_launch(void* const* d_in, const int* in_sizes, int n_in,
                              void* d_out, int out_size, void* d_ws, size_t ws_size,
                              hipStream_t stream) {
    const float* x      = (const float*)d_in[0];
    const float* xc     = (const float*)d_in[1];
    const float* W_fc   = (const float*)d_in[2];
    const float* b_fc   = (const float*)d_in[3];
    const float* W_r    = (const float*)d_in[4];
    const float* b_r    = (const float*)d_in[5];
    const float* W_g    = (const float*)d_in[6];
    const float* b_g    = (const float*)d_in[7];
    const float* W_kin  = (const float*)d_in[8];
    const float* b_kin  = (const float*)d_in[9];
    const float* W_kout = (const float*)d_in[10];
    const float* b_kout = (const float*)d_in[11];
    float* yOut = (float*)d_out;

    char* ws = (char*)d_ws;
    float*  stateK = (float*)(ws + 0);                        // 2 MB
    float*  params = (float*)(ws + (2 << 20));                // 19 planes (reserve 4 MB)
    ushort* Wt_g   = (ushort*)(ws + (6 << 20));               // 25,344 B
    ushort* whlo_g = (ushort*)(ws + (6 << 20) + (64 << 10));  // 4,096 B
    char*   p      = ws + (6 << 20) + (128 << 10);
    float2* pspl   = (float2*)p;                              // 16,384,000 B
    unsigned int* kmki = (unsigned int*)(p + 16384000);       // 131,072,000 B
    ushort* kevA   = (ushort*)(p + 16384000 + 131072000);     //  65,536,000 B

    // kA scratch lives in the kmki region: it is dead until kB writes it.
    ushort* hGh  = (ushort*)kmki;                             // 1 MB (2048*256 bf16)
    ushort* hGl  = hGh + 2048 * 256;                          // 1 MB
    ushort* WAhi = hGl + 2048 * 256;                          // 147,456 B (73728 bf16)
    ushort* WAlo = WAhi + 73728;                              // 147,456 B

    hipLaunchKernelGGL(kAw, dim3(288), dim3(256), 0, stream,
                       W_g, W_r, W_kin, W_kout, WAhi, WAlo, Wt_g, whlo_g);
    hipLaunchKernelGGL(kA1, dim3(2048), dim3(256), 0, stream,
                       xc, W_fc, b_fc, b_kin, stateK, hGh, hGl);
    hipLaunchKernelGGL(kA2, dim3(128), dim3(256), 0, stream,
                       hGh, hGl, WAhi, WAlo, b_g, b_r, params);
    hipLaunchKernelGGL(kB, dim3(128 * 50), dim3(256), 0, stream,
                       x, stateK, b_kout, Wt_g, whlo_g, params, kmki, kevA, pspl);
    hipLaunchKernelGGL(kC, dim3(512), dim3(64), 0, stream,
                       kmki, kevA, pspl, params, yOut);
}